// Round 1
// 281.813 us; speedup vs baseline: 1.0497x; 1.0497x over previous
//
#include <hip/hip_runtime.h>
#include <hip/hip_bf16.h>
#include <stdint.h>

typedef unsigned short u16;
typedef __attribute__((ext_vector_type(8))) short bf16x8;
typedef __attribute__((ext_vector_type(4))) float f32x4;
typedef __attribute__((ext_vector_type(16))) float f32x16;

static __device__ inline u16 f2bf(float f) {
  union { float f; uint32_t u; } v; v.f = f;
  uint32_t u = v.u;
  u += 0x7fffu + ((u >> 16) & 1);   // RNE
  return (u16)(u >> 16);
}

// fast 2^x -> single v_exp_f32
static __device__ inline float fast_exp2(float x) {
#if __has_builtin(__builtin_amdgcn_exp2f)
  return __builtin_amdgcn_exp2f(x);
#else
  return __expf(x * 0.6931471805599453f);
#endif
}

// pack two fp32 -> packed bf16x2
static __device__ inline uint32_t pack_bf16(float lo, float hi) {
#if __has_builtin(__builtin_amdgcn_cvt_pk_bf16_f32)
  typedef __attribute__((ext_vector_type(2))) __bf16 bf16x2_t;
  bf16x2_t r = __builtin_amdgcn_cvt_pk_bf16_f32(lo, hi);
  union { bf16x2_t v; uint32_t u; } c; c.v = r;
  return c.u;
#else
  union { float f; uint32_t u; } a, b;
  a.f = lo; b.f = hi;
  uint32_t ua = a.u + 0x8000u;
  uint32_t ub = b.u + 0x8000u;
  return __builtin_amdgcn_perm(ub, ua, 0x07060302u);
#endif
}

// cross-half exchange: x = [a_lo | b_lo_from_partner], y = [a_hi_from_partner | b_hi]
// i.e. x[lane<32]=a(own), x[lane>=32]=b(lane-32); y[lane<32]=a(lane+32), y[lane>=32]=b(own)
static __device__ __forceinline__ void plswap(uint32_t a, uint32_t b,
                                              uint32_t& x, uint32_t& y) {
#if __has_builtin(__builtin_amdgcn_permlane32_swap)
  auto r = __builtin_amdgcn_permlane32_swap(a, b, false, false);
  x = (uint32_t)r[0]; y = (uint32_t)r[1];
#else
  int h = (threadIdx.x & 63) >> 5;
  uint32_t pa = (uint32_t)__shfl_xor((int)a, 32, 64);
  uint32_t pb = (uint32_t)__shfl_xor((int)b, 32, 64);
  x = h ? pb : a;
  y = h ? b : pa;
#endif
}

// async global->LDS, 16B per lane; LDS dest must be lane-contiguous (base + lane*16)
static __device__ __forceinline__ void load_lds_128(const u16* g, u16* l) {
  __builtin_amdgcn_global_load_lds((const __attribute__((address_space(1))) void*)g,
                                   (__attribute__((address_space(3))) void*)l,
                                   16, 0, 0);
}

// ---------------- cast z fp32 -> bf16 ----------------
__global__ __launch_bounds__(256) void cast_bf16_kernel(const float* __restrict__ src,
                                                        u16* __restrict__ dst, int n4) {
  int i = blockIdx.x * 256 + threadIdx.x;
  if (i < n4) {
    float4 v = reinterpret_cast<const float4*>(src)[i];
    uint2 o;
    o.x = pack_bf16(v.x, v.y);
    o.y = pack_bf16(v.z, v.w);
    reinterpret_cast<uint2*>(dst)[i] = o;
  }
}

// ---------------- weights: transpose + cast (Bt[n][k] = W[k][n]) ----------------
__global__ __launch_bounds__(256) void wtrans_kernel(const float* __restrict__ wq,
                                                     const float* __restrict__ wk,
                                                     const float* __restrict__ wv,
                                                     const float* __restrict__ wo,
                                                     u16* __restrict__ bqkv,
                                                     u16* __restrict__ wot) {
  int z = blockIdx.z;
  const float* src = (z == 0) ? wq : (z == 1) ? wk : (z == 2) ? wv : wo;
  u16* dst = (z < 3) ? (bqkv + (size_t)z * 1024 * 1024) : wot;
  __shared__ float tile[32][33];
  int c0 = blockIdx.x * 32, r0 = blockIdx.y * 32;
  int tx = threadIdx.x, ty = threadIdx.y;
#pragma unroll
  for (int i = 0; i < 32; i += 8)
    tile[ty + i][tx] = src[(size_t)(r0 + ty + i) * 1024 + c0 + tx];
  __syncthreads();
#pragma unroll
  for (int i = 0; i < 32; i += 8)
    dst[(size_t)(c0 + ty + i) * 1024 + r0 + tx] = f2bf(tile[tx][ty + i]);
}

// ---------------- GEMM (m97 structure): C[M,N] = A[M,1024] @ Bt[N,1024]^T ----------------
template <int MODE>
__global__ __launch_bounds__(256) void gemm_bt_kernel(
    const u16* __restrict__ A, const u16* __restrict__ Bt,
    u16* __restrict__ outQ, u16* __restrict__ outK, u16* __restrict__ outVt,
    float* __restrict__ outC, const float* __restrict__ bias) {
  const int Kd = 1024;
  const int n0 = blockIdx.x * 128;
  const int m0 = blockIdx.y * 128;
  __shared__ __align__(16) u16 Asm[128 * 32];
  __shared__ __align__(16) u16 Bsm[128 * 32];
  const int tid = threadIdx.x;
  const int wave = tid >> 6, lane = tid & 63;
  const int quad = lane >> 4, l15 = lane & 15;
  const int wm = (wave >> 1) * 64, wn = (wave & 1) * 64;

  const int c0 = wave * 128 + lane;
  const int c1 = c0 + 64;
  const int r0 = c0 >> 2, p0 = (c0 & 3) * 8;
  const int r1 = c1 >> 2, p1 = (c1 & 3) * 8;

  const u16* Ab = A + (size_t)m0 * Kd;
  const u16* Bb = Bt + (size_t)n0 * Kd;

  f32x4 acc[4][4] = {};

  for (int k0 = 0; k0 < Kd; k0 += 32) {
    __syncthreads();
    load_lds_128(Ab + (size_t)r0 * Kd + k0 + p0, Asm + c0 * 8);
    load_lds_128(Ab + (size_t)r1 * Kd + k0 + p1, Asm + c1 * 8);
    load_lds_128(Bb + (size_t)r0 * Kd + k0 + p0, Bsm + c0 * 8);
    load_lds_128(Bb + (size_t)r1 * Kd + k0 + p1, Bsm + c1 * 8);
    __syncthreads();
    bf16x8 af[4], bf[4];
#pragma unroll
    for (int i = 0; i < 4; i++)
      af[i] = *reinterpret_cast<const bf16x8*>(Asm + (wm + i * 16 + l15) * 32 + quad * 8);
#pragma unroll
    for (int i = 0; i < 4; i++)
      bf[i] = *reinterpret_cast<const bf16x8*>(Bsm + (wn + i * 16 + l15) * 32 + quad * 8);
#pragma unroll
    for (int mi = 0; mi < 4; mi++)
#pragma unroll
      for (int ni = 0; ni < 4; ni++)
        acc[mi][ni] = __builtin_amdgcn_mfma_f32_16x16x32_bf16(af[mi], bf[ni], acc[mi][ni], 0, 0, 0);
  }

  if (MODE == 0) {
    const int which = (n0 + wn) >> 10;
#pragma unroll
    for (int mi = 0; mi < 4; mi++)
#pragma unroll
      for (int ni = 0; ni < 4; ni++) {
        int n = n0 + wn + ni * 16 + l15;
        int hn = n & 1023;
        int h = hn >> 6, dim = hn & 63;
        if (which == 2) {
          int m = m0 + wm + mi * 16 + quad * 4;
          int b = m >> 11, tok = m & 2047;
          uint2 pk;
          pk.x = pack_bf16(acc[mi][ni][0], acc[mi][ni][1]);
          pk.y = pack_bf16(acc[mi][ni][2], acc[mi][ni][3]);
          *reinterpret_cast<uint2*>(outVt + ((size_t)(b * 16 + h) * 64 + dim) * 2048 + tok) = pk;
        } else {
          u16* dst = (which == 0) ? outQ : outK;
          float qscale = (which == 0) ? 0.1803368801111204f : 1.0f; // 0.125*log2(e)
#pragma unroll
          for (int r = 0; r < 4; r++) {
            int m = m0 + wm + mi * 16 + quad * 4 + r;
            int b = m >> 11, tok = m & 2047;
            dst[(((size_t)(b * 16 + h)) * 2048 + tok) * 64 + dim] = f2bf(acc[mi][ni][r] * qscale);
          }
        }
      }
  } else {
#pragma unroll
    for (int mi = 0; mi < 4; mi++)
#pragma unroll
      for (int ni = 0; ni < 4; ni++) {
        int n = n0 + wn + ni * 16 + l15;
        float bv = bias[n];
#pragma unroll
        for (int r = 0; r < 4; r++) {
          int m = m0 + wm + mi * 16 + quad * 4 + r;
          outC[(size_t)m * 1024 + n] = acc[mi][ni][r] + bv;
        }
      }
  }
}

// ---------------- flash attention: 64 queries/wave, permlane exchange --------------
// Q,K: [bh][2048][64] bf16 (Q pre-scaled 0.125*log2e) ; Vt: [bh][64][2048] bf16
// out: [b][tok][h*64+dim] bf16. 256 queries/block, 64/wave (2x 32-q subtiles),
// 32x32 MFMA. K/V fragments read once from LDS, reused for both q-subtiles
// (halves LDS read traffic per MFMA vs 32-q/wave version).
// LDS: XOR-swizzled [2][64][64] K and V tiles (chunk' = chunk ^ (row&7)), staged by
// global_load_lds (swizzle applied on global source addr; LDS dest lane-contiguous).
// P never touches LDS: O^T = V^T(A) x P^T(B); B-frags built from S^T C-layout regs
// via v_permlane32_swap_b32 (one swap produces BOTH kc-half words -> zero
// ds_bpermute, zero selects; previous shfl_xor path was 8 bank-conflict
// cycles per op = 100% of the kernel's 8.4M conflicts).
__global__ __launch_bounds__(256, 2) void attn_kernel(const u16* __restrict__ Q,
                                                      const u16* __restrict__ K,
                                                      const u16* __restrict__ Vt,
                                                      u16* __restrict__ Oout) {
  const int bh = blockIdx.x;
  const int q0 = blockIdx.y * 256;
  const int tid = threadIdx.x;
  const int wave = tid >> 6, lane = tid & 63;
  const int l31 = lane & 31, h = lane >> 5;
  const int e = l31 & 7;

  __shared__ __align__(16) u16 Kb2[2][4096];   // [64 rows][64], swizzled chunks
  __shared__ __align__(16) u16 Vb2[2][4096];

  const u16* Qg = Q + ((size_t)bh * 2048 + q0 + wave * 64) * 64;
  const u16* Kg = K + (size_t)bh * 2048 * 64;
  const u16* Vg = Vt + (size_t)bh * 64 * 2048;

  // Q fragments direct from global (once per kernel), 2 q-subtiles
  bf16x8 qf[2][4];
#pragma unroll
  for (int j = 0; j < 2; j++)
#pragma unroll
    for (int dc = 0; dc < 4; dc++)
      qf[j][dc] = *reinterpret_cast<const bf16x8*>(
          Qg + (size_t)(j * 32 + l31) * 64 + dc * 16 + h * 8);

  // staging: chunk s -> LDS slot s (lane-contig), global chunk = (s&7)^(row&7)
  const int s0 = tid, s1 = tid + 256;
  const int sr0 = s0 >> 3, sg0 = ((s0 & 7) ^ (sr0 & 7)) * 8;
  const int sr1 = s1 >> 3, sg1 = ((s1 & 7) ^ (sr1 & 7)) * 8;

  load_lds_128(Kg + (size_t)sr0 * 64 + sg0, &Kb2[0][s0 * 8]);
  load_lds_128(Kg + (size_t)sr1 * 64 + sg1, &Kb2[0][s1 * 8]);
  load_lds_128(Vg + (size_t)sr0 * 2048 + sg0, &Vb2[0][s0 * 8]);
  load_lds_128(Vg + (size_t)sr1 * 2048 + sg1, &Vb2[0][s1 * 8]);
  __syncthreads();   // tile 0 resident

  float ls[2][2] = {};
  f32x16 oacc[2][2] = {};   // [j][dt]
  int cur = 0;

  for (int kt = 0; kt < 2048; kt += 64) {
    const u16* uK = &Kb2[cur][0];
    const u16* uV = &Vb2[cur][0];

    // ---- fragment reads (conflict-free via swizzle); reused for both j ----
    bf16x8 kfr[2][4], vfr[2][2][2];
#pragma unroll
    for (int kb = 0; kb < 2; kb++)
#pragma unroll
      for (int dc = 0; dc < 4; dc++)
        kfr[kb][dc] = *reinterpret_cast<const bf16x8*>(
            uK + (kb * 32 + l31) * 64 + (((2 * dc + h) ^ e) * 8));
#pragma unroll
    for (int dt = 0; dt < 2; dt++)
#pragma unroll
      for (int kb = 0; kb < 2; kb++)
#pragma unroll
        for (int kc = 0; kc < 2; kc++)
          vfr[dt][kb][kc] = *reinterpret_cast<const bf16x8*>(
              uV + (dt * 32 + l31) * 64 + (((4 * kb + 2 * kc + h) ^ e) * 8));

    // ---- async DMA next tile into other buffer (drained at loop-end barrier) ----
    if (kt + 64 < 2048) {
      const int nb = cur ^ 1;
      load_lds_128(Kg + (size_t)(kt + 64 + sr0) * 64 + sg0, &Kb2[nb][s0 * 8]);
      load_lds_128(Kg + (size_t)(kt + 64 + sr1) * 64 + sg1, &Kb2[nb][s1 * 8]);
      load_lds_128(Vg + (size_t)sr0 * 2048 + kt + 64 + sg0, &Vb2[nb][s0 * 8]);
      load_lds_128(Vg + (size_t)sr1 * 2048 + kt + 64 + sg1, &Vb2[nb][s1 * 8]);
    }

    // ---- per 32-key half x per q-subtile: S^T, softmax, permlane exchange, PV ----
#pragma unroll
    for (int kb = 0; kb < 2; kb++)
#pragma unroll
      for (int j = 0; j < 2; j++) {
        f32x16 s = {};
#pragma unroll
        for (int dc = 0; dc < 4; dc++)
          s = __builtin_amdgcn_mfma_f32_32x32x16_bf16(kfr[kb][dc], qf[j][dc], s, 0, 0, 0);
        // lane (q=l31,h) reg r holds key (r&3)+8*(r>>2)+4h (+32kb)
        float p[16];
#pragma unroll
        for (int i = 0; i < 16; i++) p[i] = fast_exp2(s[i]);
#pragma unroll
        for (int i = 0; i < 16; i += 2) { ls[j][0] += p[i]; ls[j][1] += p[i + 1]; }
        uint32_t pk[4][2];
#pragma unroll
        for (int rq = 0; rq < 4; rq++) {
          pk[rq][0] = pack_bf16(p[rq * 4 + 0], p[rq * 4 + 1]);
          pk[rq][1] = pack_bf16(p[rq * 4 + 2], p[rq * 4 + 3]);
        }
        // B-frag words (within kb): kc0 lane needs keys {8h..8h+7}:
        //   b0.x = h? partner pk1.x : own pk0.x ; b0.z = h? own pk1.x : partner pk0.x
        // -> exactly one permlane32_swap(pk0.w, pk1.w) per word pair
        uint4 b0, b1;
        plswap(pk[0][0], pk[1][0], b0.x, b0.z);
        plswap(pk[0][1], pk[1][1], b0.y, b0.w);
        plswap(pk[2][0], pk[3][0], b1.x, b1.z);
        plswap(pk[2][1], pk[3][1], b1.y, b1.w);
        union { uint4 u; bf16x8 v; } bf0, bf1;
        bf0.u = b0; bf1.u = b1;
#pragma unroll
        for (int dt = 0; dt < 2; dt++) {
          oacc[j][dt] = __builtin_amdgcn_mfma_f32_32x32x16_bf16(vfr[dt][kb][0], bf0.v, oacc[j][dt], 0, 0, 0);
          oacc[j][dt] = __builtin_amdgcn_mfma_f32_32x32x16_bf16(vfr[dt][kb][1], bf1.v, oacc[j][dt], 0, 0, 0);
        }
      }

    __syncthreads();   // joins: frag reads done (lgkm), next-tile DMA done (vmcnt)
    cur ^= 1;
  }

  // O^T layout: lane = q (l31), reg r = dim (r&3)+8*(r>>2)+4h+32dt
  const int b = bh >> 4, hd = bh & 15;
  u16* dst = Oout + (size_t)b * 2048 * 1024 + (size_t)hd * 64;
#pragma unroll
  for (int j = 0; j < 2; j++) {
    float lsum = ls[j][0] + ls[j][1];
    lsum += __shfl_xor(lsum, 32, 64);
    float inv = __builtin_amdgcn_rcpf(lsum);
    const size_t qrow = (size_t)(q0 + wave * 64 + j * 32 + l31) * 1024;
#pragma unroll
    for (int dt = 0; dt < 2; dt++)
#pragma unroll
      for (int rq = 0; rq < 4; rq++) {
        uint2 o;
        o.x = pack_bf16(oacc[j][dt][rq * 4 + 0] * inv, oacc[j][dt][rq * 4 + 1] * inv);
        o.y = pack_bf16(oacc[j][dt][rq * 4 + 2] * inv, oacc[j][dt][rq * 4 + 3] * inv);
        *reinterpret_cast<uint2*>(dst + qrow + dt * 32 + rq * 8 + h * 4) = o;
      }
  }
}

extern "C" void kernel_launch(void* const* d_in, const int* in_sizes, int n_in,
                              void* d_out, int out_size, void* d_ws, size_t ws_size,
                              hipStream_t stream) {
  (void)in_sizes; (void)n_in; (void)out_size; (void)ws_size;
  const float* z  = (const float*)d_in[0];
  const float* wq = (const float*)d_in[1];
  const float* wk = (const float*)d_in[2];
  const float* wv = (const float*)d_in[3];
  const float* wo = (const float*)d_in[4];
  const float* bo = (const float*)d_in[5];
  float* out = (float*)d_out;

  // workspace layout (72 MiB):
  char* ws = (char*)d_ws;
  u16* zb   = (u16*)(ws);                          // 16 MiB  z bf16 [8192][1024]; reused as attn_out
  u16* bqkv = (u16*)(ws + (16ull << 20));          // 6 MiB   W_qkv^T [3072][1024]
  u16* wot  = (u16*)(ws + (22ull << 20));          // 2 MiB   W_o^T   [1024][1024]
  u16* Qb   = (u16*)(ws + (24ull << 20));          // 16 MiB  [64][2048][64]
  u16* Kb   = (u16*)(ws + (40ull << 20));          // 16 MiB  [64][2048][64]
  u16* Vtb  = (u16*)(ws + (56ull << 20));          // 16 MiB  [64][64][2048] (written by GEMM)
  u16* Ob   = zb;                                  // attn_out [8192][1024]

  cast_bf16_kernel<<<8192, 256, 0, stream>>>(z, zb, 2097152);
  wtrans_kernel<<<dim3(32, 32, 4), dim3(32, 8), 0, stream>>>(wq, wk, wv, wo, bqkv, wot);
  gemm_bt_kernel<0><<<dim3(24, 64), 256, 0, stream>>>(zb, bqkv, Qb, Kb, Vtb, nullptr, nullptr);
  attn_kernel<<<dim3(64, 8), 256, 0, stream>>>(Qb, Kb, Vtb, Ob);
  gemm_bt_kernel<1><<<dim3(8, 64), 256, 0, stream>>>(Ob, wot, nullptr, nullptr, nullptr, out, bo);
}

// Round 2
// 281.621 us; speedup vs baseline: 1.0505x; 1.0007x over previous
//
#include <hip/hip_runtime.h>
#include <hip/hip_bf16.h>
#include <stdint.h>

typedef unsigned short u16;
typedef __attribute__((ext_vector_type(8))) short bf16x8;
typedef __attribute__((ext_vector_type(4))) float f32x4;
typedef __attribute__((ext_vector_type(16))) float f32x16;

static __device__ inline u16 f2bf(float f) {
  union { float f; uint32_t u; } v; v.f = f;
  uint32_t u = v.u;
  u += 0x7fffu + ((u >> 16) & 1);   // RNE
  return (u16)(u >> 16);
}

// fast 2^x -> single v_exp_f32
static __device__ inline float fast_exp2(float x) {
#if __has_builtin(__builtin_amdgcn_exp2f)
  return __builtin_amdgcn_exp2f(x);
#else
  return __expf(x * 0.6931471805599453f);
#endif
}

// pack two fp32 -> packed bf16x2
static __device__ inline uint32_t pack_bf16(float lo, float hi) {
#if __has_builtin(__builtin_amdgcn_cvt_pk_bf16_f32)
  typedef __attribute__((ext_vector_type(2))) __bf16 bf16x2_t;
  bf16x2_t r = __builtin_amdgcn_cvt_pk_bf16_f32(lo, hi);
  union { bf16x2_t v; uint32_t u; } c; c.v = r;
  return c.u;
#else
  union { float f; uint32_t u; } a, b;
  a.f = lo; b.f = hi;
  uint32_t ua = a.u + 0x8000u;
  uint32_t ub = b.u + 0x8000u;
  return __builtin_amdgcn_perm(ub, ua, 0x07060302u);
#endif
}

// cross-half exchange: x = [a_lo | b_lo_from_partner], y = [a_hi_from_partner | b_hi]
static __device__ __forceinline__ void plswap(uint32_t a, uint32_t b,
                                              uint32_t& x, uint32_t& y) {
#if __has_builtin(__builtin_amdgcn_permlane32_swap)
  auto r = __builtin_amdgcn_permlane32_swap(a, b, false, false);
  x = (uint32_t)r[0]; y = (uint32_t)r[1];
#else
  int h = (threadIdx.x & 63) >> 5;
  uint32_t pa = (uint32_t)__shfl_xor((int)a, 32, 64);
  uint32_t pb = (uint32_t)__shfl_xor((int)b, 32, 64);
  x = h ? pb : a;
  y = h ? b : pa;
#endif
}

// async global->LDS, 16B per lane; LDS dest must be lane-contiguous (base + lane*16)
static __device__ __forceinline__ void load_lds_128(const u16* g, u16* l) {
  __builtin_amdgcn_global_load_lds((const __attribute__((address_space(1))) void*)g,
                                   (__attribute__((address_space(3))) void*)l,
                                   16, 0, 0);
}

// ---------------- cast z fp32 -> bf16 ----------------
__global__ __launch_bounds__(256) void cast_bf16_kernel(const float* __restrict__ src,
                                                        u16* __restrict__ dst, int n4) {
  int i = blockIdx.x * 256 + threadIdx.x;
  if (i < n4) {
    float4 v = reinterpret_cast<const float4*>(src)[i];
    uint2 o;
    o.x = pack_bf16(v.x, v.y);
    o.y = pack_bf16(v.z, v.w);
    reinterpret_cast<uint2*>(dst)[i] = o;
  }
}

// ---------------- weights: transpose + cast (Bt[n][k] = W[k][n]) ----------------
__global__ __launch_bounds__(256) void wtrans_kernel(const float* __restrict__ wq,
                                                     const float* __restrict__ wk,
                                                     const float* __restrict__ wv,
                                                     const float* __restrict__ wo,
                                                     u16* __restrict__ bqkv,
                                                     u16* __restrict__ wot) {
  int z = blockIdx.z;
  const float* src = (z == 0) ? wq : (z == 1) ? wk : (z == 2) ? wv : wo;
  u16* dst = (z < 3) ? (bqkv + (size_t)z * 1024 * 1024) : wot;
  __shared__ float tile[32][33];
  int c0 = blockIdx.x * 32, r0 = blockIdx.y * 32;
  int tx = threadIdx.x, ty = threadIdx.y;
#pragma unroll
  for (int i = 0; i < 32; i += 8)
    tile[ty + i][tx] = src[(size_t)(r0 + ty + i) * 1024 + c0 + tx];
  __syncthreads();
#pragma unroll
  for (int i = 0; i < 32; i += 8)
    dst[(size_t)(c0 + ty + i) * 1024 + r0 + tx] = f2bf(tile[tx][ty + i]);
}

// ---------------- GEMM (m97 structure, kept for MODE 1): C = A @ Bt^T ----------------
template <int MODE>
__global__ __launch_bounds__(256) void gemm_bt_kernel(
    const u16* __restrict__ A, const u16* __restrict__ Bt,
    u16* __restrict__ outQ, u16* __restrict__ outK, u16* __restrict__ outVt,
    float* __restrict__ outC, const float* __restrict__ bias) {
  const int Kd = 1024;
  const int n0 = blockIdx.x * 128;
  const int m0 = blockIdx.y * 128;
  __shared__ __align__(16) u16 Asm[128 * 32];
  __shared__ __align__(16) u16 Bsm[128 * 32];
  const int tid = threadIdx.x;
  const int wave = tid >> 6, lane = tid & 63;
  const int quad = lane >> 4, l15 = lane & 15;
  const int wm = (wave >> 1) * 64, wn = (wave & 1) * 64;

  const int c0 = wave * 128 + lane;
  const int c1 = c0 + 64;
  const int r0 = c0 >> 2, p0 = (c0 & 3) * 8;
  const int r1 = c1 >> 2, p1 = (c1 & 3) * 8;

  const u16* Ab = A + (size_t)m0 * Kd;
  const u16* Bb = Bt + (size_t)n0 * Kd;

  f32x4 acc[4][4] = {};

  for (int k0 = 0; k0 < Kd; k0 += 32) {
    __syncthreads();
    load_lds_128(Ab + (size_t)r0 * Kd + k0 + p0, Asm + c0 * 8);
    load_lds_128(Ab + (size_t)r1 * Kd + k0 + p1, Asm + c1 * 8);
    load_lds_128(Bb + (size_t)r0 * Kd + k0 + p0, Bsm + c0 * 8);
    load_lds_128(Bb + (size_t)r1 * Kd + k0 + p1, Bsm + c1 * 8);
    __syncthreads();
    bf16x8 af[4], bf[4];
#pragma unroll
    for (int i = 0; i < 4; i++)
      af[i] = *reinterpret_cast<const bf16x8*>(Asm + (wm + i * 16 + l15) * 32 + quad * 8);
#pragma unroll
    for (int i = 0; i < 4; i++)
      bf[i] = *reinterpret_cast<const bf16x8*>(Bsm + (wn + i * 16 + l15) * 32 + quad * 8);
#pragma unroll
    for (int mi = 0; mi < 4; mi++)
#pragma unroll
      for (int ni = 0; ni < 4; ni++)
        acc[mi][ni] = __builtin_amdgcn_mfma_f32_16x16x32_bf16(af[mi], bf[ni], acc[mi][ni], 0, 0, 0);
  }

  if (MODE == 0) {
    const int which = (n0 + wn) >> 10;
#pragma unroll
    for (int mi = 0; mi < 4; mi++)
#pragma unroll
      for (int ni = 0; ni < 4; ni++) {
        int n = n0 + wn + ni * 16 + l15;
        int hn = n & 1023;
        int h = hn >> 6, dim = hn & 63;
        if (which == 2) {
          int m = m0 + wm + mi * 16 + quad * 4;
          int b = m >> 11, tok = m & 2047;
          uint2 pk;
          pk.x = pack_bf16(acc[mi][ni][0], acc[mi][ni][1]);
          pk.y = pack_bf16(acc[mi][ni][2], acc[mi][ni][3]);
          *reinterpret_cast<uint2*>(outVt + ((size_t)(b * 16 + h) * 64 + dim) * 2048 + tok) = pk;
        } else {
          u16* dst = (which == 0) ? outQ : outK;
          float qscale = (which == 0) ? 0.1803368801111204f : 1.0f; // 0.125*log2(e)
#pragma unroll
          for (int r = 0; r < 4; r++) {
            int m = m0 + wm + mi * 16 + quad * 4 + r;
            int b = m >> 11, tok = m & 2047;
            dst[(((size_t)(b * 16 + h)) * 2048 + tok) * 64 + dim] = f2bf(acc[mi][ni][r] * qscale);
          }
        }
      }
  } else {
#pragma unroll
    for (int mi = 0; mi < 4; mi++)
#pragma unroll
      for (int ni = 0; ni < 4; ni++) {
        int n = n0 + wn + ni * 16 + l15;
        float bv = bias[n];
#pragma unroll
        for (int r = 0; r < 4; r++) {
          int m = m0 + wm + mi * 16 + quad * 4 + r;
          outC[(size_t)m * 1024 + n] = acc[mi][ni][r] + bv;
        }
      }
  }
}

// ---------------- 256x256 8-phase GEMM (QKV projection, MODE-0 epilogue) ------------
// C[M=8192, N=3072] = A[M,1024] @ Bt[N,1024]^T, bf16 -> Q/K/Vt split write.
// 512 thr = 8 waves (2M x 4N), per-wave 128x64 out, acc[8][4] f32x4.
// BK=64, 2 K-tiles/iter, 8 phases/iter; per phase: ds-reads -> barrier ->
// lgkmcnt(0) -> setprio(1) 16xMFMA setprio(0) -> barrier. LDS 128 KiB
// (2 dbuf x {A,B} x 2 halves x 128x64). XOR chunk-swizzle (chunk^=row&7) applied
// on the global SOURCE address; LDS stays lane-linear for global_load_lds.
// vmcnt ledger (per-iter, 16 stage-loads): B-halves die after ph2 -> stage
// buf.B<-tileT+2 at ph3; A-halves die after ph3 -> stage buf.A at ph4;
// mirrored at ph7/ph8 for buf1<-T+3. vmcnt(8) at ph4/ph8 leaves exactly the
// newest 8 loads (next tiles) in flight and guarantees the tile about to be
// read has landed. Never drains to 0 in the loop (T4).
__global__ __launch_bounds__(512, 2) void gemm256_kernel(
    const u16* __restrict__ A, const u16* __restrict__ Bt,
    u16* __restrict__ outQ, u16* __restrict__ outK, u16* __restrict__ outVt) {
  const int tid = threadIdx.x;
  const int lane = tid & 63;
  const int wave = tid >> 6;
  const int quad = lane >> 4, l15 = lane & 15;
  const int e15 = l15 & 7;
  const int wm = wave >> 2;     // 0..1 M-half
  const int wn = wave & 3;      // 0..3 N-slice

  // XCD-aware bijective swizzle (grid 12x32 = 384 blocks, 384 % 8 == 0)
  unsigned lin = blockIdx.y * gridDim.x + blockIdx.x;
  unsigned nwg = gridDim.x * gridDim.y;
  lin = (lin & 7u) * (nwg >> 3) + (lin >> 3);
  const int bx = lin % gridDim.x, by = lin / gridDim.x;
  const int n0 = bx * 256, m0 = by * 256;

  __shared__ __align__(16) u16 AsmL[2][16384];   // [buf][half*8192 + row*64 + slot*8]
  __shared__ __align__(16) u16 BsmL[2][16384];
  u16* const As_[2] = {&AsmL[0][0], &AsmL[1][0]};
  u16* const Bs_[2] = {&BsmL[0][0], &BsmL[1][0]};

  const u16* Abase = A + (size_t)m0 * 1024;
  const u16* Bbase = Bt + (size_t)n0 * 1024;

  const int awoff = wm * 8192;
  const int bwoff = (wn >> 1) * 8192 + (wn & 1) * 4096;

  f32x4 acc[8][4] = {};
  bf16x8 af[4][2], bfr[4][2];

#define STG_HALF(ldsp, gp)                                                      \
  {                                                                             \
    const int cs0 = tid, cs1 = tid + 512;                                       \
    const int r0_ = cs0 >> 3, g0_ = (((cs0 & 7) ^ (r0_ & 7)) << 3);             \
    const int r1_ = cs1 >> 3, g1_ = (((cs1 & 7) ^ (r1_ & 7)) << 3);             \
    load_lds_128((gp) + (size_t)r0_ * 1024 + g0_, (ldsp) + cs0 * 8);            \
    load_lds_128((gp) + (size_t)r1_ * 1024 + g1_, (ldsp) + cs1 * 8);            \
  }

#define PHB() do { asm volatile("" ::: "memory"); __builtin_amdgcn_s_barrier(); \
                   asm volatile("" ::: "memory"); } while (0)
#define LGKM0() asm volatile("s_waitcnt lgkmcnt(0)" ::: "memory")
#define VMC8()  asm volatile("s_waitcnt vmcnt(8)" ::: "memory")

#define RD_A(mb, B)                                                             \
  _Pragma("unroll") for (int x = 0; x < 4; x++)                                 \
  _Pragma("unroll") for (int kk = 0; kk < 2; kk++)                              \
    af[x][kk] = *reinterpret_cast<const bf16x8*>(                               \
        As_[B] + awoff + (((mb) + x) * 16 + l15) * 64 + (((quad + kk * 4) ^ e15) << 3));

#define RD_B(nb, B)                                                             \
  _Pragma("unroll") for (int x = 0; x < 2; x++)                                 \
  _Pragma("unroll") for (int kk = 0; kk < 2; kk++)                              \
    bfr[(nb) + x][kk] = *reinterpret_cast<const bf16x8*>(                       \
        Bs_[B] + bwoff + (((nb) + x) * 16 + l15) * 64 + (((quad + kk * 4) ^ e15) << 3));

#define MM(mb, nb)                                                              \
  _Pragma("unroll") for (int kk = 0; kk < 2; kk++)                              \
  _Pragma("unroll") for (int x = 0; x < 4; x++)                                 \
  _Pragma("unroll") for (int y = 0; y < 2; y++)                                 \
    acc[(mb) + x][(nb) + y] = __builtin_amdgcn_mfma_f32_16x16x32_bf16(          \
        af[x][kk], bfr[(nb) + y][kk], acc[(mb) + x][(nb) + y], 0, 0, 0);

#define TILE4(B, KS)                                                            \
  RD_A(0, B); RD_B(0, B);                                                       \
  PHB(); LGKM0(); __builtin_amdgcn_s_setprio(1); MM(0, 0);                      \
  __builtin_amdgcn_s_setprio(0); PHB();                                         \
  RD_B(2, B);                                                                   \
  PHB(); LGKM0(); __builtin_amdgcn_s_setprio(1); MM(0, 2);                      \
  __builtin_amdgcn_s_setprio(0); PHB();                                         \
  RD_A(4, B);                                                                   \
  STG_HALF(Bs_[B], Bbase + (KS)); STG_HALF(Bs_[B] + 8192, Bbase + 128 * 1024 + (KS)); \
  PHB(); LGKM0(); __builtin_amdgcn_s_setprio(1); MM(4, 0);                      \
  __builtin_amdgcn_s_setprio(0); PHB();                                         \
  STG_HALF(As_[B], Abase + (KS)); STG_HALF(As_[B] + 8192, Abase + 128 * 1024 + (KS)); \
  PHB(); __builtin_amdgcn_s_setprio(1); MM(4, 2);                               \
  __builtin_amdgcn_s_setprio(0); VMC8(); PHB();

  // prologue: tile0 -> buf0 (oldest 8 loads), tile1 -> buf1
  STG_HALF(As_[0], Abase);      STG_HALF(As_[0] + 8192, Abase + 128 * 1024);
  STG_HALF(Bs_[0], Bbase);      STG_HALF(Bs_[0] + 8192, Bbase + 128 * 1024);
  STG_HALF(As_[1], Abase + 64); STG_HALF(As_[1] + 8192, Abase + 128 * 1024 + 64);
  STG_HALF(Bs_[1], Bbase + 64); STG_HALF(Bs_[1] + 8192, Bbase + 128 * 1024 + 64);
  VMC8(); PHB();

#pragma unroll 1
  for (int it = 0; it < 8; ++it) {
    int t2 = it * 2 + 2; if (t2 > 15) t2 = 15;   // clamped: tail re-stages valid
    int t3 = it * 2 + 3; if (t3 > 15) t3 = 15;   // data into dead slots (never read)
    const int k2 = t2 * 64, k3 = t3 * 64;
    TILE4(0, k2);
    TILE4(1, k3);
  }

  // -------- MODE-0 epilogue: split Q / K / Vt --------
  const int which = (n0 + wn * 64) >> 10;
#pragma unroll
  for (int mi = 0; mi < 8; mi++)
#pragma unroll
    for (int ni = 0; ni < 4; ni++) {
      int n = n0 + wn * 64 + ni * 16 + l15;
      int hn = n & 1023;
      int hh = hn >> 6, dim = hn & 63;
      if (which == 2) {
        int m = m0 + wm * 128 + mi * 16 + quad * 4;
        int b = m >> 11, tok = m & 2047;
        uint2 pk;
        pk.x = pack_bf16(acc[mi][ni][0], acc[mi][ni][1]);
        pk.y = pack_bf16(acc[mi][ni][2], acc[mi][ni][3]);
        *reinterpret_cast<uint2*>(outVt + ((size_t)(b * 16 + hh) * 64 + dim) * 2048 + tok) = pk;
      } else {
        u16* dst = (which == 0) ? outQ : outK;
        float qscale = (which == 0) ? 0.1803368801111204f : 1.0f; // 0.125*log2(e)
#pragma unroll
        for (int r = 0; r < 4; r++) {
          int m = m0 + wm * 128 + mi * 16 + quad * 4 + r;
          int b = m >> 11, tok = m & 2047;
          dst[(((size_t)(b * 16 + hh)) * 2048 + tok) * 64 + dim] = f2bf(acc[mi][ni][r] * qscale);
        }
      }
    }
#undef STG_HALF
#undef PHB
#undef LGKM0
#undef VMC8
#undef RD_A
#undef RD_B
#undef MM
#undef TILE4
}

// ---------------- flash attention: 64 queries/wave, permlane exchange --------------
__global__ __launch_bounds__(256, 2) void attn_kernel(const u16* __restrict__ Q,
                                                      const u16* __restrict__ K,
                                                      const u16* __restrict__ Vt,
                                                      u16* __restrict__ Oout) {
  const int bh = blockIdx.x;
  const int q0 = blockIdx.y * 256;
  const int tid = threadIdx.x;
  const int wave = tid >> 6, lane = tid & 63;
  const int l31 = lane & 31, h = lane >> 5;
  const int e = l31 & 7;

  __shared__ __align__(16) u16 Kb2[2][4096];   // [64 rows][64], swizzled chunks
  __shared__ __align__(16) u16 Vb2[2][4096];

  const u16* Qg = Q + ((size_t)bh * 2048 + q0 + wave * 64) * 64;
  const u16* Kg = K + (size_t)bh * 2048 * 64;
  const u16* Vg = Vt + (size_t)bh * 64 * 2048;

  bf16x8 qf[2][4];
#pragma unroll
  for (int j = 0; j < 2; j++)
#pragma unroll
    for (int dc = 0; dc < 4; dc++)
      qf[j][dc] = *reinterpret_cast<const bf16x8*>(
          Qg + (size_t)(j * 32 + l31) * 64 + dc * 16 + h * 8);

  const int s0 = tid, s1 = tid + 256;
  const int sr0 = s0 >> 3, sg0 = ((s0 & 7) ^ (sr0 & 7)) * 8;
  const int sr1 = s1 >> 3, sg1 = ((s1 & 7) ^ (sr1 & 7)) * 8;

  load_lds_128(Kg + (size_t)sr0 * 64 + sg0, &Kb2[0][s0 * 8]);
  load_lds_128(Kg + (size_t)sr1 * 64 + sg1, &Kb2[0][s1 * 8]);
  load_lds_128(Vg + (size_t)sr0 * 2048 + sg0, &Vb2[0][s0 * 8]);
  load_lds_128(Vg + (size_t)sr1 * 2048 + sg1, &Vb2[0][s1 * 8]);
  __syncthreads();   // tile 0 resident

  float ls[2][2] = {};
  f32x16 oacc[2][2] = {};   // [j][dt]
  int cur = 0;

  for (int kt = 0; kt < 2048; kt += 64) {
    const u16* uK = &Kb2[cur][0];
    const u16* uV = &Vb2[cur][0];

    bf16x8 kfr[2][4], vfr[2][2][2];
#pragma unroll
    for (int kb = 0; kb < 2; kb++)
#pragma unroll
      for (int dc = 0; dc < 4; dc++)
        kfr[kb][dc] = *reinterpret_cast<const bf16x8*>(
            uK + (kb * 32 + l31) * 64 + (((2 * dc + h) ^ e) * 8));
#pragma unroll
    for (int dt = 0; dt < 2; dt++)
#pragma unroll
      for (int kb = 0; kb < 2; kb++)
#pragma unroll
        for (int kc = 0; kc < 2; kc++)
          vfr[dt][kb][kc] = *reinterpret_cast<const bf16x8*>(
              uV + (dt * 32 + l31) * 64 + (((4 * kb + 2 * kc + h) ^ e) * 8));

    if (kt + 64 < 2048) {
      const int nb = cur ^ 1;
      load_lds_128(Kg + (size_t)(kt + 64 + sr0) * 64 + sg0, &Kb2[nb][s0 * 8]);
      load_lds_128(Kg + (size_t)(kt + 64 + sr1) * 64 + sg1, &Kb2[nb][s1 * 8]);
      load_lds_128(Vg + (size_t)sr0 * 2048 + kt + 64 + sg0, &Vb2[nb][s0 * 8]);
      load_lds_128(Vg + (size_t)sr1 * 2048 + kt + 64 + sg1, &Vb2[nb][s1 * 8]);
    }

#pragma unroll
    for (int kb = 0; kb < 2; kb++)
#pragma unroll
      for (int j = 0; j < 2; j++) {
        f32x16 s = {};
#pragma unroll
        for (int dc = 0; dc < 4; dc++)
          s = __builtin_amdgcn_mfma_f32_32x32x16_bf16(kfr[kb][dc], qf[j][dc], s, 0, 0, 0);
        float p[16];
#pragma unroll
        for (int i = 0; i < 16; i++) p[i] = fast_exp2(s[i]);
#pragma unroll
        for (int i = 0; i < 16; i += 2) { ls[j][0] += p[i]; ls[j][1] += p[i + 1]; }
        uint32_t pk[4][2];
#pragma unroll
        for (int rq = 0; rq < 4; rq++) {
          pk[rq][0] = pack_bf16(p[rq * 4 + 0], p[rq * 4 + 1]);
          pk[rq][1] = pack_bf16(p[rq * 4 + 2], p[rq * 4 + 3]);
        }
        uint4 b0, b1;
        plswap(pk[0][0], pk[1][0], b0.x, b0.z);
        plswap(pk[0][1], pk[1][1], b0.y, b0.w);
        plswap(pk[2][0], pk[3][0], b1.x, b1.z);
        plswap(pk[2][1], pk[3][1], b1.y, b1.w);
        union { uint4 u; bf16x8 v; } bf0, bf1;
        bf0.u = b0; bf1.u = b1;
#pragma unroll
        for (int dt = 0; dt < 2; dt++) {
          oacc[j][dt] = __builtin_amdgcn_mfma_f32_32x32x16_bf16(vfr[dt][kb][0], bf0.v, oacc[j][dt], 0, 0, 0);
          oacc[j][dt] = __builtin_amdgcn_mfma_f32_32x32x16_bf16(vfr[dt][kb][1], bf1.v, oacc[j][dt], 0, 0, 0);
        }
      }

    __syncthreads();
    cur ^= 1;
  }

  const int b = bh >> 4, hd = bh & 15;
  u16* dst = Oout + (size_t)b * 2048 * 1024 + (size_t)hd * 64;
#pragma unroll
  for (int j = 0; j < 2; j++) {
    float lsum = ls[j][0] + ls[j][1];
    lsum += __shfl_xor(lsum, 32, 64);
    float inv = __builtin_amdgcn_rcpf(lsum);
    const size_t qrow = (size_t)(q0 + wave * 64 + j * 32 + l31) * 1024;
#pragma unroll
    for (int dt = 0; dt < 2; dt++)
#pragma unroll
      for (int rq = 0; rq < 4; rq++) {
        uint2 o;
        o.x = pack_bf16(oacc[j][dt][rq * 4 + 0] * inv, oacc[j][dt][rq * 4 + 1] * inv);
        o.y = pack_bf16(oacc[j][dt][rq * 4 + 2] * inv, oacc[j][dt][rq * 4 + 3] * inv);
        *reinterpret_cast<uint2*>(dst + qrow + dt * 32 + rq * 8 + h * 4) = o;
      }
  }
}

extern "C" void kernel_launch(void* const* d_in, const int* in_sizes, int n_in,
                              void* d_out, int out_size, void* d_ws, size_t ws_size,
                              hipStream_t stream) {
  (void)in_sizes; (void)n_in; (void)out_size; (void)ws_size;
  const float* z  = (const float*)d_in[0];
  const float* wq = (const float*)d_in[1];
  const float* wk = (const float*)d_in[2];
  const float* wv = (const float*)d_in[3];
  const float* wo = (const float*)d_in[4];
  const float* bo = (const float*)d_in[5];
  float* out = (float*)d_out;

  // workspace layout (72 MiB):
  char* ws = (char*)d_ws;
  u16* zb   = (u16*)(ws);                          // 16 MiB  z bf16 [8192][1024]; reused as attn_out
  u16* bqkv = (u16*)(ws + (16ull << 20));          // 6 MiB   W_qkv^T [3072][1024]
  u16* wot  = (u16*)(ws + (22ull << 20));          // 2 MiB   W_o^T   [1024][1024]
  u16* Qb   = (u16*)(ws + (24ull << 20));          // 16 MiB  [64][2048][64]
  u16* Kb   = (u16*)(ws + (40ull << 20));          // 16 MiB  [64][2048][64]
  u16* Vtb  = (u16*)(ws + (56ull << 20));          // 16 MiB  [64][64][2048] (written by GEMM)
  u16* Ob   = zb;                                  // attn_out [8192][1024]

  cast_bf16_kernel<<<8192, 256, 0, stream>>>(z, zb, 2097152);
  wtrans_kernel<<<dim3(32, 32, 4), dim3(32, 8), 0, stream>>>(wq, wk, wv, wo, bqkv, wot);
  gemm256_kernel<<<dim3(12, 32), 512, 0, stream>>>(zb, bqkv, Qb, Kb, Vtb);
  attn_kernel<<<dim3(64, 8), 256, 0, stream>>>(Qb, Kb, Vtb, Ob);
  gemm_bt_kernel<1><<<dim3(8, 64), 256, 0, stream>>>(Ob, wot, nullptr, nullptr, nullptr, out, bo);
}